// Round 13
// baseline (1112.364 us; speedup 1.0000x reference)
//
#include <hip/hip_runtime.h>
#include <math.h>

#define NN 1000
#define INF_ 32
#define H 128
#define M 128
#define DEG 16
#define PP 2
#define OUTF 10
#define MAXM (10 * NN)        // scan length; head <= MAXM
#define QCAP (MAXM + DEG)     // only entries < MAXM are ever read
#define NSLOT (MAXM + 128)    // nmbuf rows: nstart + total procs
#define NT 512                // 8 waves (R12: 1024 threads => regalloc spill)
#define RCH 32                // rows per chunk: two 16-row tiles per wave
#define WROW 264              // padded halves per X row (256+8)
#define NROW 136              // padded halves per NSh row (128+8)

typedef _Float16 half8 __attribute__((ext_vector_type(8)));
typedef float floatx4 __attribute__((ext_vector_type(4)));

// LDS-only barrier: publishes LDS writes without draining global (vmcnt) queue.
__device__ __forceinline__ void bar_lds() {
    asm volatile("s_waitcnt lgkmcnt(0)\n\ts_barrier" ::: "memory");
}

// Fully fused: encoder + weight-frag load + rank-decomposed sequential ACT
// loop (MFMA matvecs, register-resident B-frags, 2 LDS barriers per 32-row
// chunk) + readout. ws: feats_h f16 | finalv f32 | nmbuf_h f16 | qpack u32.
__global__ __launch_bounds__(NT, 2)   // min 2 waves/EU -> 256 VGPR budget
void seq_kernel(const float* __restrict__ xa, const float* __restrict__ fm,
                const int* __restrict__ neighbors, const int* __restrict__ nstart_p,
                const float* __restrict__ enc_w, const float* __restrict__ enc_b,
                const float* __restrict__ ns_w, const float* __restrict__ ns_b,
                const float* __restrict__ nm_w, const float* __restrict__ nm_b,
                const float* __restrict__ act_w, const float* __restrict__ act_b,
                const float* __restrict__ dec_w, const float* __restrict__ dec_b,
                _Float16* __restrict__ feats_h, float* __restrict__ finalv,
                _Float16* __restrict__ nmbuf_h, unsigned int* __restrict__ qpack,
                float* __restrict__ out) {
    __shared__ __align__(16) _Float16 s_Xh[RCH * WROW];  // 16896 B
    __shared__ __align__(16) _Float16 s_NSh[RCH * NROW]; // 8704 B
    __shared__ float s_tact[NN];                         // 4000 B
    __shared__ int   s_mark[NN];                         // 4000 B (order/readout overlay)
    __shared__ float s_rz[RCH];
    __shared__ float s_rta[NT];                          // round-start tact per row
    __shared__ unsigned short s_rnode[NT];
    __shared__ unsigned short s_rslot[NT];
    __shared__ unsigned int  s_enq[NT];                  // node|newslot<<16 per entry
    __shared__ unsigned char s_flag[NT];
    __shared__ int s_wb[8], s_wc[8];

    short* s_order = (short*)s_mark;                     // overlay: mark[0..255]
    float* s_g  = (float*)(s_mark + 256);                // overlay: readout only
    float* s_lg = (float*)(s_mark + 256 + 128);

    const int t = threadIdx.x;
    const int lane = t & 63, wid = t >> 6;               // wid 0..7
    const int quad = lane >> 4, lm = lane & 15;
    const int colw = (wid << 4) + lm;                    // this thread's output col
    const int sg = t & 31;                               // gate sub-lane
    const int r32 = t >> 5, c8 = t & 31;                 // staging coords (16x32)
    const int nstart = nstart_p[0];

    // ---- prologue 1: weight B-fragments f32->fp16 directly into registers ----
    half8 wbn[8], wbm[8];
#pragma unroll
    for (int c = 0; c < 8; ++c) {
#pragma unroll
        for (int j = 0; j < 8; ++j) {
            const int k = (c << 5) + (quad << 3) + j;
            wbn[c][j] = (_Float16)ns_w[k * H + colw];    // RTNE, same as pack
            wbm[c][j] = (_Float16)nm_w[k * M + colw];
        }
    }
    // ---- prologue 2: encoder, finalv zero, first messages, queue init ----
    {
        const int h = t & 127, b0 = t >> 7;              // 4 node-groups
        float ew[INF_];
#pragma unroll
        for (int k = 0; k < INF_; ++k) ew[k] = enc_w[k * H + h];
        const float eb = enc_b[h];
        for (int b = b0; b < NN; b += 4) {
            float acc = eb;
            const float* xr = xa + b * INF_;
#pragma unroll
            for (int k = 0; k < INF_; ++k) acc += xr[k] * ew[k];
            feats_h[b * H + h] = (_Float16)acc;          // same rounding as R8..R12
        }
        for (int i = t; i < NN * H; i += NT) finalv[i] = 0.0f;
        for (int i = t; i < nstart * M; i += NT) nmbuf_h[i] = (_Float16)fm[i];
    }
    for (int i = t; i < NN; i += NT) { s_tact[i] = 0.0f; s_mark[i] = 0x7fffffff; }
    for (int i = t; i < nstart; i += NT) qpack[i] = (unsigned)i | ((unsigned)i << 16);
    const float actb = act_b[0];
    const float nsb_c = ns_b[colw];
    const float nmb_c = nm_b[colw];
    float aw[8];
#pragma unroll
    for (int j = 0; j < 8; ++j) aw[j] = act_w[sg * 8 + j];
    __syncthreads();                                     // drain prologue writes

    int head = 0, tail = nstart, gbase = nstart;
    for (;;) {
        const int lim = min(tail, MAXM);
        if (head >= lim) break;
        const int W = min(NT, lim - head);

        // ---- classify; clear flags; repair order-overlaid mark ----
        int node = 0, slotv = 0; bool cand0 = false;
        if (t < W) {
            const unsigned v = qpack[head + t];
            node = (int)(v & 0xffffu);
            slotv = (int)(v >> 16);
            cand0 = (s_tact[node] <= 1.0f - 1e-7f);
        }
        s_flag[t] = 0;
        if (t < 256) s_mark[t] = 0x7fffffff;
        bar_lds();                                       // B1
        bool remaining = cand0;

        // ---------------- rank rounds ----------------
        int base = 0;
        for (;;) {
            float tav = 0.0f;
            bool rem2 = false;
            if (remaining) { tav = s_tact[node]; rem2 = (tav <= 1.0f - 1e-7f); }
            if (rem2) atomicMin(&s_mark[node], t);
            bar_lds();                                   // R1
            const bool win = rem2 && (s_mark[node] == t);
            const unsigned long long mw = __ballot(win);
            if (lane == 0) s_wb[wid] = __popcll(mw);
            bar_lds();                                   // R2
            int Pr = 0, preb = 0;
#pragma unroll
            for (int w = 0; w < 8; ++w) { Pr += s_wb[w]; preb += (w < wid) ? s_wb[w] : 0; }
            if (Pr == 0) break;
            const int wrank = preb + __popcll(mw & ((1ull << lane) - 1ull));
            if (win) {
                s_rnode[wrank] = (unsigned short)node;
                s_rslot[wrank] = (unsigned short)slotv;
                s_rta[wrank] = tav;
                s_enq[t] = (unsigned)node | ((unsigned)(gbase + base + wrank) << 16);
                s_flag[t] = 1;
            }
            if (rem2) s_mark[node] = 0x7fffffff;         // reset touched entries
            remaining = rem2 && !win;
            bar_lds();                                   // R3: rnode/rslot/rta ready

            // ---- prefetch chunk 0 X rows (two 16-row tiles) ----
            uint4 px[2];
#pragma unroll
            for (int j = 0; j < 2; ++j) {
                const int rr = min(r32 + 16 * j, Pr - 1);
                const int nr = (int)s_rnode[rr];
                const int sl = (int)s_rslot[rr];
                px[j] = (c8 < 16)
                    ? ((const uint4*)(feats_h + (size_t)nr * H))[c8]
                    : ((const uint4*)(nmbuf_h + (size_t)sl * M))[c8 - 16];
            }
            // ---- chunks of 32 rows ----
            for (int c0 = 0; c0 < Pr; c0 += RCH) {
                const int Pc = min(RCH, Pr - c0);
#pragma unroll
                for (int j = 0; j < 2; ++j)
                    *(uint4*)(s_Xh + (r32 + 16 * j) * WROW + (c8 << 3)) = px[j];
                // finalv prefetch (used in epilogue; latency hidden by chunk body)
                float fv[8];
#pragma unroll
                for (int i = 0; i < 4; ++i) {
                    fv[i]     = finalv[(size_t)s_rnode[min(c0 + (quad << 2) + i, Pr - 1)] * H + colw];
                    fv[4 + i] = finalv[(size_t)s_rnode[min(c0 + 16 + (quad << 2) + i, Pr - 1)] * H + colw];
                }
                bar_lds();                               // A: Xh ready (no vmcnt drain)
                const bool hasnext = (c0 + RCH) < Pr;
                uint4 pxn[2];
                if (hasnext) {
#pragma unroll
                    for (int j = 0; j < 2; ++j) {
                        const int rr = min(c0 + RCH + r32 + 16 * j, Pr - 1);
                        const int nr = (int)s_rnode[rr];
                        const int sl = (int)s_rslot[rr];
                        pxn[j] = (c8 < 16)
                            ? ((const uint4*)(feats_h + (size_t)nr * H))[c8]
                            : ((const uint4*)(nmbuf_h + (size_t)sl * M))[c8 - 16];
                    }
                }
                // gate partials (f32 math on fp16 x; coeffs in regs), 2 row passes
                for (int r = t >> 5; r < Pc; r += 16) {
                    const half8 hv = *(const half8*)(s_Xh + r * WROW + (sg << 3));
                    float p = 0.0f;
#pragma unroll
                    for (int j = 0; j < 8; ++j) p += (float)hv[j] * aw[j];
#pragma unroll
                    for (int off = 16; off > 0; off >>= 1) p += __shfl_down(p, off, 32);
                    if (sg == 0) s_rz[r] = p;
                }
                // phase 1 MFMA: two independent interleaved chains (tiles 0/1)
                floatx4 accn0 = {0,0,0,0}, accm0 = {0,0,0,0};
                floatx4 accn1 = {0,0,0,0}, accm1 = {0,0,0,0};
                {
                    const _Float16* x0 = s_Xh + lm * WROW + (quad << 3);
                    const _Float16* x1 = s_Xh + (16 + lm) * WROW + (quad << 3);
                    half8 a0[8], a1[8];
#pragma unroll
                    for (int c = 0; c < 8; ++c) {
                        a0[c] = *(const half8*)(x0 + (c << 5));
                        a1[c] = *(const half8*)(x1 + (c << 5));
                    }
#pragma unroll
                    for (int c = 0; c < 8; ++c) {
                        accn0 = __builtin_amdgcn_mfma_f32_16x16x32_f16(a0[c], wbn[c], accn0, 0, 0, 0);
                        accn1 = __builtin_amdgcn_mfma_f32_16x16x32_f16(a1[c], wbn[c], accn1, 0, 0, 0);
                    }
#pragma unroll
                    for (int c = 4; c < 8; ++c) {
                        accm0 = __builtin_amdgcn_mfma_f32_16x16x32_f16(a0[c], wbm[c], accm0, 0, 0, 0);
                        accm1 = __builtin_amdgcn_mfma_f32_16x16x32_f16(a1[c], wbm[c], accm1, 0, 0, 0);
                    }
                }
                float nsv[8];
#pragma unroll
                for (int i = 0; i < 4; ++i) {
                    const int r0 = (quad << 2) + i;
                    nsv[i] = fmaxf(accn0[i] + nsb_c, 0.0f);
                    if (r0 < Pc) {
                        s_NSh[r0 * NROW + colw] = (_Float16)nsv[i];
                        feats_h[(size_t)s_rnode[c0 + r0] * H + colw] = (_Float16)nsv[i];
                    }
                    const int r1 = r0 + 16;
                    nsv[4 + i] = fmaxf(accn1[i] + nsb_c, 0.0f);
                    if (r1 < Pc) {
                        s_NSh[r1 * NROW + colw] = (_Float16)nsv[4 + i];
                        feats_h[(size_t)s_rnode[c0 + r1] * H + colw] = (_Float16)nsv[4 + i];
                    }
                }
                bar_lds();                               // B: NSh + rz ready

                // tact update (single writer per node; ordered by R7 full sync)
                if (t < Pc) {
                    const float z = s_rz[t] + actb;
                    const float cnd = 1.0f / (1.0f + expf(-z));
                    const float ta = s_rta[c0 + t];
                    const float nat = (ta + cnd > 1.0f) ? (1.0f - ta) : cnd;
                    s_tact[(int)s_rnode[c0 + t]] = ta + nat;
                }
                // phase 2 MFMA: nm ns-half, both tiles
                {
                    const _Float16* n0 = s_NSh + lm * NROW + (quad << 3);
                    const _Float16* n1 = s_NSh + (16 + lm) * NROW + (quad << 3);
#pragma unroll
                    for (int c = 0; c < 4; ++c) {
                        accm0 = __builtin_amdgcn_mfma_f32_16x16x32_f16(
                            *(const half8*)(n0 + (c << 5)), wbm[c], accm0, 0, 0, 0);
                        accm1 = __builtin_amdgcn_mfma_f32_16x16x32_f16(
                            *(const half8*)(n1 + (c << 5)), wbm[c], accm1, 0, 0, 0);
                    }
                }
                // epilogue: new_act recomputed (bit-identical); nmbuf + finalv
#pragma unroll
                for (int i = 0; i < 4; ++i) {
                    const int r0 = (quad << 2) + i;
                    if (r0 < Pc) {
                        const float z = s_rz[r0] + actb;
                        const float cnd = 1.0f / (1.0f + expf(-z));
                        const float ta = s_rta[c0 + r0];
                        const float na = (ta + cnd > 1.0f) ? (1.0f - ta) : cnd;
                        nmbuf_h[(size_t)(gbase + base + c0 + r0) * M + colw] =
                            (_Float16)(accm0[i] + nmb_c);
                        finalv[(size_t)s_rnode[c0 + r0] * H + colw] = fv[i] + nsv[i] * na;
                    }
                    const int r1 = r0 + 16;
                    if (r1 < Pc) {
                        const float z = s_rz[r1] + actb;
                        const float cnd = 1.0f / (1.0f + expf(-z));
                        const float ta = s_rta[c0 + r1];
                        const float na = (ta + cnd > 1.0f) ? (1.0f - ta) : cnd;
                        nmbuf_h[(size_t)(gbase + base + c0 + r1) * M + colw] =
                            (_Float16)(accm1[i] + nmb_c);
                        finalv[(size_t)s_rnode[c0 + r1] * H + colw] = fv[4 + i] + nsv[4 + i] * na;
                    }
                }
                if (hasnext) { px[0] = pxn[0]; px[1] = pxn[1]; }
            }
            base += Pr;
            __syncthreads();       // R7 (full): drain feats/nmbuf/finalv stores
        }

        // ---------------- enqueue (queue order via prefix over flags) ----------------
        const bool pf = (s_flag[t] != 0);
        const unsigned long long mf = __ballot(pf);
        if (lane == 0) s_wc[wid] = __popcll(mf);
        bar_lds();                                       // B3
        int T = 0, prec = 0;
#pragma unroll
        for (int w = 0; w < 8; ++w) { T += s_wc[w]; prec += (w < wid) ? s_wc[w] : 0; }
        if (pf) s_order[prec + __popcll(mf & ((1ull << lane) - 1ull))] = (short)t;
        bar_lds();                                       // B4
        for (int idx = t; idx < T * DEG; idx += NT) {
            const int e = (int)s_order[idx >> 4];
            const unsigned v = s_enq[e];
            const int nd = (int)(v & 0xffffu);
            const unsigned slot = v >> 16;
            const int q = tail + idx;
            if (q < QCAP)
                qpack[q] = (unsigned)neighbors[nd * DEG + (idx & 15)] | (slot << 16);
        }
        tail += DEG * T;
        gbase += T;
        head += W;
        __syncthreads();                                 // B5 (full): qpack visible
    }

    // ---- readout (g/lg overlaid on dead mark region) ----
    if (t < H) {
        float g0 = 0, g1 = 0, g2 = 0, g3 = 0;
        for (int n = 0; n < NN; n += 4) {
            g0 += finalv[(n + 0) * H + t];
            g1 += finalv[(n + 1) * H + t];
            g2 += finalv[(n + 2) * H + t];
            g3 += finalv[(n + 3) * H + t];
        }
        s_g[t] = (g0 + g1) + (g2 + g3);
    }
    __syncthreads();
    if (t < PP * OUTF) {
        const int pp = t / OUTF, o = t % OUTF;
        float acc = dec_b[pp * OUTF + o];
        for (int h = 0; h < H; ++h) acc += s_g[h] * dec_w[(pp * H + h) * OUTF + o];
        s_lg[t] = acc;
    }
    __syncthreads();
    if (t < PP * OUTF) {
        const int pp = t / OUTF;
        float mx = -INFINITY;
        for (int o = 0; o < OUTF; ++o) mx = fmaxf(mx, s_lg[pp * OUTF + o]);
        float s = 0.0f;
        for (int o = 0; o < OUTF; ++o) s += expf(s_lg[pp * OUTF + o] - mx);
        out[t] = s_lg[t] - (mx + logf(s));
    }
}

extern "C" void kernel_launch(void* const* d_in, const int* in_sizes, int n_in,
                              void* d_out, int out_size, void* d_ws, size_t ws_size,
                              hipStream_t stream) {
    const float* xa        = (const float*)d_in[0];
    const float* fm        = (const float*)d_in[1];
    const int*   neighbors = (const int*)  d_in[2];
    const int*   nstart_p  = (const int*)  d_in[3];
    const float* enc_w     = (const float*)d_in[4];
    const float* enc_b     = (const float*)d_in[5];
    const float* ns_w      = (const float*)d_in[6];
    const float* ns_b      = (const float*)d_in[7];
    const float* nm_w      = (const float*)d_in[8];
    const float* nm_b      = (const float*)d_in[9];
    const float* act_w     = (const float*)d_in[10];
    const float* act_b     = (const float*)d_in[11];
    const float* dec_w     = (const float*)d_in[12];
    const float* dec_b     = (const float*)d_in[13];
    float* out = (float*)d_out;

    char* w = (char*)d_ws;
    _Float16* feats_h = (_Float16*)w;                 w += (size_t)NN * H * 2;
    float*    finalv  = (float*)w;                    w += (size_t)NN * H * 4;
    _Float16* nmbuf_h = (_Float16*)w;                 w += (size_t)NSLOT * M * 2;
    unsigned int* qpack = (unsigned int*)w;

    seq_kernel<<<1, NT, 0, stream>>>(xa, fm, neighbors, nstart_p,
                                     enc_w, enc_b, ns_w, ns_b, nm_w, nm_b,
                                     act_w, act_b, dec_w, dec_b,
                                     feats_h, finalv, nmbuf_h, qpack, out);
}

// Round 14
// 878.404 us; speedup vs baseline: 1.2663x; 1.2663x over previous
//
#include <hip/hip_runtime.h>
#include <math.h>

#define NN 1000
#define INF_ 32
#define H 128
#define M 128
#define DEG 16
#define PP 2
#define OUTF 10
#define MAXM (10 * NN)        // scan length; head <= MAXM
#define QCAP (MAXM + DEG)     // only entries < MAXM are ever read
#define NSLOT (MAXM + 128)    // nmbuf rows: nstart + total procs
#define NT 512                // 8 waves; keep steady-state VGPR < 128 (R12/R13 lesson)
#define WROW 264              // padded halves per X row (256+8)
#define NROW 136              // padded halves per NSh row (128+8)

typedef _Float16 half8 __attribute__((ext_vector_type(8)));
typedef float floatx4 __attribute__((ext_vector_type(4)));

// LDS-only barrier: publishes LDS writes without draining global (vmcnt) queue.
__device__ __forceinline__ void bar_lds() {
    asm volatile("s_waitcnt lgkmcnt(0)\n\ts_barrier" ::: "memory");
}

// Fused single kernel: prologue (encoder with dead-before-sync registers;
// weight B-frags f32->fp16 into regs AFTER the sync) + rank-decomposed
// sequential ACT loop (R11 structure, 16-row chunks, single MFMA chain,
// 2 LDS barriers per chunk) + readout.
// ws: feats_h f16 | finalv f32 | nmbuf_h f16 | qpack u32 (node | slot<<16)
__global__ __launch_bounds__(NT, 1)
void seq_kernel(const float* __restrict__ xa, const float* __restrict__ fm,
                const int* __restrict__ neighbors, const int* __restrict__ nstart_p,
                const float* __restrict__ enc_w, const float* __restrict__ enc_b,
                const float* __restrict__ ns_w, const float* __restrict__ ns_b,
                const float* __restrict__ nm_w, const float* __restrict__ nm_b,
                const float* __restrict__ act_w, const float* __restrict__ act_b,
                const float* __restrict__ dec_w, const float* __restrict__ dec_b,
                _Float16* __restrict__ feats_h, float* __restrict__ finalv,
                _Float16* __restrict__ nmbuf_h, unsigned int* __restrict__ qpack,
                float* __restrict__ out) {
    __shared__ __align__(16) _Float16 s_Xh[16 * WROW];   // 8448 B
    __shared__ __align__(16) _Float16 s_NSh[16 * NROW];  // 4352 B
    __shared__ float s_tact[NN];                         // 4000 B
    __shared__ int   s_mark[NN];                         // 4000 B (order/readout overlay)
    __shared__ float s_rz[16];
    __shared__ float s_rta[NT];                          // round-start tact per row
    __shared__ unsigned short s_rnode[NT];
    __shared__ unsigned short s_rslot[NT];
    __shared__ unsigned int  s_enq[NT];                  // node|newslot<<16 per entry
    __shared__ unsigned char s_flag[NT];
    __shared__ int s_wb[8], s_wc[8];

    short* s_order = (short*)s_mark;                     // overlay: mark[0..127]
    float* s_g  = (float*)(s_mark + 256);                // overlay: readout only
    float* s_lg = (float*)(s_mark + 256 + 128);

    const int t = threadIdx.x;
    const int lane = t & 63, wid = t >> 6;
    const int quad = lane >> 4, lm = lane & 15;
    const int colw = (wid << 4) + lm;                    // this thread's output col
    const int sg = t & 31;                               // gate sub-lane
    const int r16 = t >> 5, c8 = t & 31;                 // staging coords (16x32)
    const int nstart = nstart_p[0];

    // ---- prologue A: encoder / finalv zero / first messages (regs die here) ----
    {
        const int h = t & 127, b0 = t >> 7;              // 4 node-groups
        float ew[INF_];
#pragma unroll
        for (int k = 0; k < INF_; ++k) ew[k] = enc_w[k * H + h];
        const float eb = enc_b[h];
        for (int b = b0; b < NN; b += 4) {
            float acc = eb;
            const float* xr = xa + b * INF_;
#pragma unroll
            for (int k = 0; k < INF_; ++k) acc += xr[k] * ew[k];
            feats_h[b * H + h] = (_Float16)acc;          // same rounding as R8..R13
        }
        for (int i = t; i < NN * H; i += NT) finalv[i] = 0.0f;
        for (int i = t; i < nstart * M; i += NT) nmbuf_h[i] = (_Float16)fm[i];
    }
    for (int i = t; i < NN; i += NT) { s_tact[i] = 0.0f; s_mark[i] = 0x7fffffff; }
    for (int i = t; i < nstart; i += NT) qpack[i] = (unsigned)i | ((unsigned)i << 16);
    __syncthreads();                                     // drain prologue; kill ew[]

    // ---- prologue B: weight B-fragments f32->fp16 directly into registers ----
    half8 wbn[8], wbm[8];
#pragma unroll
    for (int c = 0; c < 8; ++c) {
#pragma unroll
        for (int j = 0; j < 8; ++j) {
            const int k = (c << 5) + (quad << 3) + j;
            wbn[c][j] = (_Float16)ns_w[k * H + colw];    // RTNE, same as pack_kernel
            wbm[c][j] = (_Float16)nm_w[k * M + colw];
        }
    }
    const float actb = act_b[0];
    const float nsb_c = ns_b[colw];
    const float nmb_c = nm_b[colw];
    float aw[8];
#pragma unroll
    for (int j = 0; j < 8; ++j) aw[j] = act_w[sg * 8 + j];

    int head = 0, tail = nstart, gbase = nstart;
    for (;;) {
        const int lim = min(tail, MAXM);
        if (head >= lim) break;
        const int W = min(NT, lim - head);

        // ---- classify; clear flags; repair order-overlaid mark ----
        int node = 0, slotv = 0; bool cand0 = false;
        if (t < W) {
            const unsigned v = qpack[head + t];
            node = (int)(v & 0xffffu);
            slotv = (int)(v >> 16);
            cand0 = (s_tact[node] <= 1.0f - 1e-7f);
        }
        s_flag[t] = 0;
        if (t < 256) s_mark[t] = 0x7fffffff;
        bar_lds();                                       // B1
        bool remaining = cand0;

        // ---------------- rank rounds ----------------
        int base = 0;
        for (;;) {
            float tav = 0.0f;
            bool rem2 = false;
            if (remaining) { tav = s_tact[node]; rem2 = (tav <= 1.0f - 1e-7f); }
            if (rem2) atomicMin(&s_mark[node], t);
            bar_lds();                                   // R1
            const bool win = rem2 && (s_mark[node] == t);
            const unsigned long long mw = __ballot(win);
            if (lane == 0) s_wb[wid] = __popcll(mw);
            bar_lds();                                   // R2
            int Pr = 0, preb = 0;
#pragma unroll
            for (int w = 0; w < 8; ++w) { Pr += s_wb[w]; preb += (w < wid) ? s_wb[w] : 0; }
            if (Pr == 0) break;
            const int wrank = preb + __popcll(mw & ((1ull << lane) - 1ull));
            if (win) {
                s_rnode[wrank] = (unsigned short)node;
                s_rslot[wrank] = (unsigned short)slotv;
                s_rta[wrank] = tav;
                s_enq[t] = (unsigned)node | ((unsigned)(gbase + base + wrank) << 16);
                s_flag[t] = 1;
            }
            if (rem2) s_mark[node] = 0x7fffffff;         // reset touched entries
            remaining = rem2 && !win;
            bar_lds();                                   // R3: rnode/rslot/rta ready

            // ---- prefetch chunk 0 (X row uint4 + finalv vals) ----
            uint4 px; float fv[4];
            {
                const int rr = min(r16, Pr - 1);
                const int nr = (int)s_rnode[rr];
                const int sl = (int)s_rslot[rr];
                px = (c8 < 16)
                    ? ((const uint4*)(feats_h + (size_t)nr * H))[c8]
                    : ((const uint4*)(nmbuf_h + (size_t)sl * M))[c8 - 16];
#pragma unroll
                for (int i = 0; i < 4; ++i) {
                    const int rr2 = min((quad << 2) + i, Pr - 1);
                    fv[i] = finalv[(size_t)s_rnode[rr2] * H + colw];
                }
            }
            // ---- chunks of 16 rows, software-pipelined staging ----
            for (int c0 = 0; c0 < Pr; c0 += 16) {
                const int Pc = min(16, Pr - c0);
                *(uint4*)(s_Xh + r16 * WROW + (c8 << 3)) = px;
                bar_lds();                               // A: Xh(c) ready
                const bool hasnext = (c0 + 16) < Pr;
                uint4 pxn; float fvn[4];
                if (hasnext) {                           // issue next-chunk loads
                    const int rr = min(c0 + 16 + r16, Pr - 1);
                    const int nr = (int)s_rnode[rr];
                    const int sl = (int)s_rslot[rr];
                    pxn = (c8 < 16)
                        ? ((const uint4*)(feats_h + (size_t)nr * H))[c8]
                        : ((const uint4*)(nmbuf_h + (size_t)sl * M))[c8 - 16];
#pragma unroll
                    for (int i = 0; i < 4; ++i) {
                        const int rr2 = min(c0 + 16 + (quad << 2) + i, Pr - 1);
                        fvn[i] = finalv[(size_t)s_rnode[rr2] * H + colw];
                    }
                }
                // gate partials (f32 math on fp16 x; coeffs in regs)
                {
                    const int r = t >> 5;
                    if (r < Pc) {
                        const half8 hv = *(const half8*)(s_Xh + r * WROW + (sg << 3));
                        float p = 0.0f;
#pragma unroll
                        for (int j = 0; j < 8; ++j) p += (float)hv[j] * aw[j];
#pragma unroll
                        for (int off = 16; off > 0; off >>= 1) p += __shfl_down(p, off, 32);
                        if (sg == 0) s_rz[r] = p;
                    }
                }
                // phase 1 MFMA: ns (K=256) + nm msg-half (K=128..256); B from regs
                floatx4 accn = {0.0f, 0.0f, 0.0f, 0.0f};
                floatx4 accm = {0.0f, 0.0f, 0.0f, 0.0f};
                {
                    const _Float16* xrow = s_Xh + lm * WROW + (quad << 3);
                    half8 a[8];
#pragma unroll
                    for (int c = 0; c < 8; ++c) a[c] = *(const half8*)(xrow + (c << 5));
#pragma unroll
                    for (int c = 0; c < 8; ++c)
                        accn = __builtin_amdgcn_mfma_f32_16x16x32_f16(
                            a[c], wbn[c], accn, 0, 0, 0);
#pragma unroll
                    for (int c = 4; c < 8; ++c)
                        accm = __builtin_amdgcn_mfma_f32_16x16x32_f16(
                            a[c], wbm[c], accm, 0, 0, 0);
                }
                float nsv[4];
#pragma unroll
                for (int i = 0; i < 4; ++i) {
                    const int r = (quad << 2) + i;
                    nsv[i] = fmaxf(accn[i] + nsb_c, 0.0f);
                    if (r < Pc) {
                        s_NSh[r * NROW + colw] = (_Float16)nsv[i];
                        feats_h[(size_t)s_rnode[c0 + r] * H + colw] = (_Float16)nsv[i];
                    }
                }
                bar_lds();                               // B: Xh reads done; NSh+rz ready

                // tact update (single writer per node; ordered by R7 full sync)
                if (t < Pc) {
                    const float z = s_rz[t] + actb;
                    const float cnd = 1.0f / (1.0f + expf(-z));
                    const float ta = s_rta[c0 + t];
                    const float nat = (ta + cnd > 1.0f) ? (1.0f - ta) : cnd;
                    s_tact[(int)s_rnode[c0 + t]] = ta + nat;
                }
                // phase 2 MFMA: nm ns-half (K=0..128); B from regs
                {
                    const _Float16* nrow = s_NSh + lm * NROW + (quad << 3);
#pragma unroll
                    for (int c = 0; c < 4; ++c)
                        accm = __builtin_amdgcn_mfma_f32_16x16x32_f16(
                            *(const half8*)(nrow + (c << 5)), wbm[c], accm, 0, 0, 0);
                }
                // epilogue (no barrier C): new_act recomputed bit-identically
#pragma unroll
                for (int i = 0; i < 4; ++i) {
                    const int r = (quad << 2) + i;
                    if (r < Pc) {
                        const float z = s_rz[r] + actb;
                        const float cnd = 1.0f / (1.0f + expf(-z));
                        const float ta = s_rta[c0 + r];
                        const float na = (ta + cnd > 1.0f) ? (1.0f - ta) : cnd;
                        nmbuf_h[(size_t)(gbase + base + c0 + r) * M + colw] =
                            (_Float16)(accm[i] + nmb_c);
                        finalv[(size_t)s_rnode[c0 + r] * H + colw] =
                            fv[i] + nsv[i] * na;
                    }
                }
                if (hasnext) {
                    px = pxn;
#pragma unroll
                    for (int i = 0; i < 4; ++i) fv[i] = fvn[i];
                }
            }
            base += Pr;
            __syncthreads();       // R7 (full): drain feats/nmbuf/finalv stores
        }

        // ---------------- enqueue (queue order via prefix over flags) ----------------
        const bool pf = (s_flag[t] != 0);
        const unsigned long long mf = __ballot(pf);
        if (lane == 0) s_wc[wid] = __popcll(mf);
        bar_lds();                                       // B3
        int T = 0, prec = 0;
#pragma unroll
        for (int w = 0; w < 8; ++w) { T += s_wc[w]; prec += (w < wid) ? s_wc[w] : 0; }
        if (pf) s_order[prec + __popcll(mf & ((1ull << lane) - 1ull))] = (short)t;
        bar_lds();                                       // B4
        for (int idx = t; idx < T * DEG; idx += NT) {
            const int e = (int)s_order[idx >> 4];
            const unsigned v = s_enq[e];
            const int nd = (int)(v & 0xffffu);
            const unsigned slot = v >> 16;
            const int q = tail + idx;
            if (q < QCAP)
                qpack[q] = (unsigned)neighbors[nd * DEG + (idx & 15)] | (slot << 16);
        }
        tail += DEG * T;
        gbase += T;
        head += W;
        __syncthreads();                                 // B5 (full): qpack visible
    }

    // ---- readout (g/lg overlaid on dead mark region) ----
    if (t < H) {
        float g0 = 0, g1 = 0, g2 = 0, g3 = 0;
        for (int n = 0; n < NN; n += 4) {
            g0 += finalv[(n + 0) * H + t];
            g1 += finalv[(n + 1) * H + t];
            g2 += finalv[(n + 2) * H + t];
            g3 += finalv[(n + 3) * H + t];
        }
        s_g[t] = (g0 + g1) + (g2 + g3);
    }
    __syncthreads();
    if (t < PP * OUTF) {
        const int pp = t / OUTF, o = t % OUTF;
        float acc = dec_b[pp * OUTF + o];
        for (int h = 0; h < H; ++h) acc += s_g[h] * dec_w[(pp * H + h) * OUTF + o];
        s_lg[t] = acc;
    }
    __syncthreads();
    if (t < PP * OUTF) {
        const int pp = t / OUTF;
        float mx = -INFINITY;
        for (int o = 0; o < OUTF; ++o) mx = fmaxf(mx, s_lg[pp * OUTF + o]);
        float s = 0.0f;
        for (int o = 0; o < OUTF; ++o) s += expf(s_lg[pp * OUTF + o] - mx);
        out[t] = s_lg[t] - (mx + logf(s));
    }
}

extern "C" void kernel_launch(void* const* d_in, const int* in_sizes, int n_in,
                              void* d_out, int out_size, void* d_ws, size_t ws_size,
                              hipStream_t stream) {
    const float* xa        = (const float*)d_in[0];
    const float* fm        = (const float*)d_in[1];
    const int*   neighbors = (const int*)  d_in[2];
    const int*   nstart_p  = (const int*)  d_in[3];
    const float* enc_w     = (const float*)d_in[4];
    const float* enc_b     = (const float*)d_in[5];
    const float* ns_w      = (const float*)d_in[6];
    const float* ns_b      = (const float*)d_in[7];
    const float* nm_w      = (const float*)d_in[8];
    const float* nm_b      = (const float*)d_in[9];
    const float* act_w     = (const float*)d_in[10];
    const float* act_b     = (const float*)d_in[11];
    const float* dec_w     = (const float*)d_in[12];
    const float* dec_b     = (const float*)d_in[13];
    float* out = (float*)d_out;

    char* w = (char*)d_ws;
    _Float16* feats_h = (_Float16*)w;                 w += (size_t)NN * H * 2;
    float*    finalv  = (float*)w;                    w += (size_t)NN * H * 4;
    _Float16* nmbuf_h = (_Float16*)w;                 w += (size_t)NSLOT * M * 2;
    unsigned int* qpack = (unsigned int*)w;

    seq_kernel<<<1, NT, 0, stream>>>(xa, fm, neighbors, nstart_p,
                                     enc_w, enc_b, ns_w, ns_b, nm_w, nm_b,
                                     act_w, act_b, dec_w, dec_b,
                                     feats_h, finalv, nmbuf_h, qpack, out);
}

// Round 15
// 753.122 us; speedup vs baseline: 1.4770x; 1.1663x over previous
//
#include <hip/hip_runtime.h>
#include <math.h>

#define NN 1000
#define INF_ 32
#define H 128
#define M 128
#define DEG 16
#define PP 2
#define OUTF 10
#define MAXM (10 * NN)        // scan length; head <= MAXM
#define QCAP (MAXM + DEG)     // only entries < MAXM are ever read
#define NSLOT (MAXM + 128)    // nmbuf rows: nstart + total procs
#define NT 512                // 8 waves; steady-state VGPR < 128 (R12/R13 lesson)
#define WROW 264              // padded halves per X row (256+8)
#define NROW 136              // padded halves per NSh row (128+8)

typedef _Float16 half8 __attribute__((ext_vector_type(8)));
typedef float floatx4 __attribute__((ext_vector_type(4)));

// LDS-only barrier: publishes LDS writes without draining global (vmcnt) queue.
__device__ __forceinline__ void bar_lds() {
    asm volatile("s_waitcnt lgkmcnt(0)\n\ts_barrier" ::: "memory");
}

// Parallel across the GPU (R14 lesson: do NOT serialize this into seq_kernel).
__global__ __launch_bounds__(128)
void init_kernel(const float* __restrict__ xa, const float* __restrict__ fm,
                 const float* __restrict__ enc_w, const float* __restrict__ enc_b,
                 const int* __restrict__ nstart_p,
                 _Float16* __restrict__ feats_h, float* __restrict__ finalv,
                 _Float16* __restrict__ nmbuf_h) {
    int b = blockIdx.x, t = threadIdx.x;
    float acc = enc_b[t];
    const float* xr = xa + b * INF_;
#pragma unroll
    for (int k = 0; k < INF_; ++k) acc += xr[k] * enc_w[k * H + t];
    feats_h[b * H + t] = (_Float16)acc;     // same rounding as R8..R14
    finalv[b * H + t] = 0.0f;
    if (b < nstart_p[0]) nmbuf_h[(size_t)b * M + t] = (_Float16)fm[b * M + t];
}

// Rank-decomposed sequential ACT loop; MFMA matvecs, register-resident weight
// B-fragments (converted f32->fp16 RTNE in prologue — cheap, verified no-remat);
// epoch-tagged node marks (no resets, no deferral race); atomicAdd round rank
// (no R2 barrier); 2 LDS barriers per 16-row chunk (no barrier C).
__global__ __launch_bounds__(NT, 1)
void seq_kernel(const int* __restrict__ neighbors, const int* __restrict__ nstart_p,
                const float* __restrict__ ns_w, const float* __restrict__ ns_b,
                const float* __restrict__ nm_w, const float* __restrict__ nm_b,
                const float* __restrict__ act_w, const float* __restrict__ act_b,
                const float* __restrict__ dec_w, const float* __restrict__ dec_b,
                _Float16* __restrict__ feats_h, float* __restrict__ finalv,
                _Float16* __restrict__ nmbuf_h, unsigned int* __restrict__ qpack,
                float* __restrict__ out) {
    __shared__ __align__(16) _Float16 s_Xh[16 * WROW];   // 8448 B
    __shared__ __align__(16) _Float16 s_NSh[16 * NROW];  // 4352 B
    __shared__ float s_tact[NN];                         // 4000 B
    __shared__ int   s_mark[NN];                         // 4000 B (readout overlay)
    __shared__ float s_rz[16];
    __shared__ float s_rta[NT];                          // round-start tact per row
    __shared__ unsigned short s_rnode[NT];
    __shared__ unsigned short s_rslot[NT];
    __shared__ unsigned int  s_enq[NT];                  // node|newslot<<16 per entry
    __shared__ unsigned char s_flag[NT];
    __shared__ int s_wc[8];
    __shared__ int s_cnt;

    short* s_order = (short*)s_rta;                      // overlay: dead between windows
    float* s_g  = (float*)(s_mark);                      // overlay: readout only
    float* s_lg = (float*)(s_mark + 128);

    const int t = threadIdx.x;
    const int lane = t & 63, wid = t >> 6;
    const int quad = lane >> 4, lm = lane & 15;
    const int colw = (wid << 4) + lm;                    // this thread's output col
    const int sg = t & 31;                               // gate sub-lane
    const int r16 = t >> 5, c8 = t & 31;                 // staging coords (16x32)
    const int nstart = nstart_p[0];

    // ---- prologue: weight B-fragments f32->fp16 directly into registers ----
    half8 wbn[8], wbm[8];
#pragma unroll
    for (int c = 0; c < 8; ++c) {
#pragma unroll
        for (int j = 0; j < 8; ++j) {
            const int k = (c << 5) + (quad << 3) + j;
            wbn[c][j] = (_Float16)ns_w[k * H + colw];    // RTNE, same as pack_kernel
            wbm[c][j] = (_Float16)nm_w[k * M + colw];
        }
    }
    for (int i = t; i < NN; i += NT) { s_tact[i] = 0.0f; s_mark[i] = 0x7fffffff; }
    for (int i = t; i < nstart; i += NT) qpack[i] = (unsigned)i | ((unsigned)i << 16);
    const float actb = act_b[0];
    const float nsb_c = ns_b[colw];
    const float nmb_c = nm_b[colw];
    float aw[8];
#pragma unroll
    for (int j = 0; j < 8; ++j) aw[j] = act_w[sg * 8 + j];
    __syncthreads();

    int head = 0, tail = nstart, gbase = nstart;
    int epoch = 0;                                       // global round counter
    for (;;) {
        const int lim = min(tail, MAXM);
        if (head >= lim) break;
        const int W = min(NT, lim - head);

        // ---- classify; clear flags ----
        int node = 0, slotv = 0; bool cand0 = false;
        if (t < W) {
            const unsigned v = qpack[head + t];
            node = (int)(v & 0xffffu);
            slotv = (int)(v >> 16);
            cand0 = (s_tact[node] <= 1.0f - 1e-7f);
        }
        s_flag[t] = 0;
        bar_lds();                                       // B1
        bool remaining = cand0;

        // ---------------- rank rounds ----------------
        int base = 0;
        for (;;) {
            ++epoch;                                     // < 32768 total rounds
            const int ec = ((0x7fff - epoch) << 16) | t; // smaller = newer epoch
            float tav = 0.0f;
            bool rem2 = false;
            if (remaining) { tav = s_tact[node]; rem2 = (tav <= 1.0f - 1e-7f); }
            if (t == 0) s_cnt = 0;
            if (rem2) atomicMin(&s_mark[node], ec);
            bar_lds();                                   // R1
            const bool win = rem2 && (s_mark[node] == ec);  // stale epochs never match
            if (win) {
                const int wrank = atomicAdd(&s_cnt, 1);  // arbitrary row order: safe
                s_rnode[wrank] = (unsigned short)node;
                s_rslot[wrank] = (unsigned short)slotv;
                s_rta[wrank] = tav;
                s_enq[t] = (unsigned)node | ((unsigned)(gbase + base + wrank) << 16);
                s_flag[t] = 1;
            }
            remaining = rem2 && !win;
            bar_lds();                                   // R3: cnt/rnode/rslot/rta ready
            const int Pr = s_cnt;
            if (Pr == 0) break;

            // ---- prefetch chunk 0 (X row uint4 + finalv vals) ----
            uint4 px; float fv[4];
            {
                const int rr = min(r16, Pr - 1);
                const int nr = (int)s_rnode[rr];
                const int sl = (int)s_rslot[rr];
                px = (c8 < 16)
                    ? ((const uint4*)(feats_h + (size_t)nr * H))[c8]
                    : ((const uint4*)(nmbuf_h + (size_t)sl * M))[c8 - 16];
#pragma unroll
                for (int i = 0; i < 4; ++i) {
                    const int rr2 = min((quad << 2) + i, Pr - 1);
                    fv[i] = finalv[(size_t)s_rnode[rr2] * H + colw];
                }
            }
            // ---- chunks of 16 rows, software-pipelined staging ----
            for (int c0 = 0; c0 < Pr; c0 += 16) {
                const int Pc = min(16, Pr - c0);
                *(uint4*)(s_Xh + r16 * WROW + (c8 << 3)) = px;
                bar_lds();                               // A: Xh(c) ready
                const bool hasnext = (c0 + 16) < Pr;
                uint4 pxn; float fvn[4];
                if (hasnext) {                           // issue next-chunk loads
                    const int rr = min(c0 + 16 + r16, Pr - 1);
                    const int nr = (int)s_rnode[rr];
                    const int sl = (int)s_rslot[rr];
                    pxn = (c8 < 16)
                        ? ((const uint4*)(feats_h + (size_t)nr * H))[c8]
                        : ((const uint4*)(nmbuf_h + (size_t)sl * M))[c8 - 16];
#pragma unroll
                    for (int i = 0; i < 4; ++i) {
                        const int rr2 = min(c0 + 16 + (quad << 2) + i, Pr - 1);
                        fvn[i] = finalv[(size_t)s_rnode[rr2] * H + colw];
                    }
                }
                // gate partials (f32 math on fp16 x; coeffs in regs)
                {
                    const int r = t >> 5;
                    if (r < Pc) {
                        const half8 hv = *(const half8*)(s_Xh + r * WROW + (sg << 3));
                        float p = 0.0f;
#pragma unroll
                        for (int j = 0; j < 8; ++j) p += (float)hv[j] * aw[j];
#pragma unroll
                        for (int off = 16; off > 0; off >>= 1) p += __shfl_down(p, off, 32);
                        if (sg == 0) s_rz[r] = p;
                    }
                }
                // phase 1 MFMA: ns (K=256) + nm msg-half (K=128..256); B from regs
                floatx4 accn = {0.0f, 0.0f, 0.0f, 0.0f};
                floatx4 accm = {0.0f, 0.0f, 0.0f, 0.0f};
                {
                    const _Float16* xrow = s_Xh + lm * WROW + (quad << 3);
                    half8 a[8];
#pragma unroll
                    for (int c = 0; c < 8; ++c) a[c] = *(const half8*)(xrow + (c << 5));
#pragma unroll
                    for (int c = 0; c < 8; ++c)
                        accn = __builtin_amdgcn_mfma_f32_16x16x32_f16(
                            a[c], wbn[c], accn, 0, 0, 0);
#pragma unroll
                    for (int c = 4; c < 8; ++c)
                        accm = __builtin_amdgcn_mfma_f32_16x16x32_f16(
                            a[c], wbm[c], accm, 0, 0, 0);
                }
                float nsv[4];
#pragma unroll
                for (int i = 0; i < 4; ++i) {
                    const int r = (quad << 2) + i;
                    nsv[i] = fmaxf(accn[i] + nsb_c, 0.0f);
                    if (r < Pc) {
                        s_NSh[r * NROW + colw] = (_Float16)nsv[i];
                        feats_h[(size_t)s_rnode[c0 + r] * H + colw] = (_Float16)nsv[i];
                    }
                }
                bar_lds();                               // B: Xh reads done; NSh+rz ready

                // tact update (single writer per node; ordered by R7 full sync)
                if (t < Pc) {
                    const float z = s_rz[t] + actb;
                    const float cnd = 1.0f / (1.0f + expf(-z));
                    const float ta = s_rta[c0 + t];
                    const float nat = (ta + cnd > 1.0f) ? (1.0f - ta) : cnd;
                    s_tact[(int)s_rnode[c0 + t]] = ta + nat;
                }
                // phase 2 MFMA: nm ns-half (K=0..128); B from regs
                {
                    const _Float16* nrow = s_NSh + lm * NROW + (quad << 3);
#pragma unroll
                    for (int c = 0; c < 4; ++c)
                        accm = __builtin_amdgcn_mfma_f32_16x16x32_f16(
                            *(const half8*)(nrow + (c << 5)), wbm[c], accm, 0, 0, 0);
                }
                // epilogue (no barrier C): new_act recomputed bit-identically
#pragma unroll
                for (int i = 0; i < 4; ++i) {
                    const int r = (quad << 2) + i;
                    if (r < Pc) {
                        const float z = s_rz[r] + actb;
                        const float cnd = 1.0f / (1.0f + expf(-z));
                        const float ta = s_rta[c0 + r];
                        const float na = (ta + cnd > 1.0f) ? (1.0f - ta) : cnd;
                        nmbuf_h[(size_t)(gbase + base + c0 + r) * M + colw] =
                            (_Float16)(accm[i] + nmb_c);
                        finalv[(size_t)s_rnode[c0 + r] * H + colw] =
                            fv[i] + nsv[i] * na;
                    }
                }
                if (hasnext) {
                    px = pxn;
#pragma unroll
                    for (int i = 0; i < 4; ++i) fv[i] = fvn[i];
                }
            }
            base += Pr;
            __syncthreads();       // R7 (full): drain feats/nmbuf/finalv stores
        }

        // ---------------- enqueue (queue order via prefix over flags) ----------------
        const bool pf = (s_flag[t] != 0);
        const unsigned long long mf = __ballot(pf);
        if (lane == 0) s_wc[wid] = __popcll(mf);
        bar_lds();                                       // B3
        int T = 0, prec = 0;
#pragma unroll
        for (int w = 0; w < 8; ++w) { T += s_wc[w]; prec += (w < wid) ? s_wc[w] : 0; }
        if (pf) s_order[prec + __popcll(mf & ((1ull << lane) - 1ull))] = (short)t;
        bar_lds();                                       // B4
        for (int idx = t; idx < T * DEG; idx += NT) {
            const int e = (int)s_order[idx >> 4];
            const unsigned v = s_enq[e];
            const int nd = (int)(v & 0xffffu);
            const unsigned slot = v >> 16;
            const int q = tail + idx;
            if (q < QCAP)
                qpack[q] = (unsigned)neighbors[nd * DEG + (idx & 15)] | (slot << 16);
        }
        tail += DEG * T;
        gbase += T;
        head += W;
        __syncthreads();                                 // B5 (full): qpack visible
    }

    // ---- readout (g/lg overlaid on dead mark region) ----
    if (t < H) {
        float g0 = 0, g1 = 0, g2 = 0, g3 = 0;
        for (int n = 0; n < NN; n += 4) {
            g0 += finalv[(n + 0) * H + t];
            g1 += finalv[(n + 1) * H + t];
            g2 += finalv[(n + 2) * H + t];
            g3 += finalv[(n + 3) * H + t];
        }
        s_g[t] = (g0 + g1) + (g2 + g3);
    }
    __syncthreads();
    if (t < PP * OUTF) {
        const int pp = t / OUTF, o = t % OUTF;
        float acc = dec_b[pp * OUTF + o];
        for (int h = 0; h < H; ++h) acc += s_g[h] * dec_w[(pp * H + h) * OUTF + o];
        s_lg[t] = acc;
    }
    __syncthreads();
    if (t < PP * OUTF) {
        const int pp = t / OUTF;
        float mx = -INFINITY;
        for (int o = 0; o < OUTF; ++o) mx = fmaxf(mx, s_lg[pp * OUTF + o]);
        float s = 0.0f;
        for (int o = 0; o < OUTF; ++o) s += expf(s_lg[pp * OUTF + o] - mx);
        out[t] = s_lg[t] - (mx + logf(s));
    }
}

extern "C" void kernel_launch(void* const* d_in, const int* in_sizes, int n_in,
                              void* d_out, int out_size, void* d_ws, size_t ws_size,
                              hipStream_t stream) {
    const float* xa        = (const float*)d_in[0];
    const float* fm        = (const float*)d_in[1];
    const int*   neighbors = (const int*)  d_in[2];
    const int*   nstart_p  = (const int*)  d_in[3];
    const float* enc_w     = (const float*)d_in[4];
    const float* enc_b     = (const float*)d_in[5];
    const float* ns_w      = (const float*)d_in[6];
    const float* ns_b      = (const float*)d_in[7];
    const float* nm_w      = (const float*)d_in[8];
    const float* nm_b      = (const float*)d_in[9];
    const float* act_w     = (const float*)d_in[10];
    const float* act_b     = (const float*)d_in[11];
    const float* dec_w     = (const float*)d_in[12];
    const float* dec_b     = (const float*)d_in[13];
    float* out = (float*)d_out;

    char* w = (char*)d_ws;
    _Float16* feats_h = (_Float16*)w;                 w += (size_t)NN * H * 2;
    float*    finalv  = (float*)w;                    w += (size_t)NN * H * 4;
    _Float16* nmbuf_h = (_Float16*)w;                 w += (size_t)NSLOT * M * 2;
    unsigned int* qpack = (unsigned int*)w;

    init_kernel<<<NN, 128, 0, stream>>>(xa, fm, enc_w, enc_b, nstart_p,
                                        feats_h, finalv, nmbuf_h);
    seq_kernel<<<1, NT, 0, stream>>>(neighbors, nstart_p,
                                     ns_w, ns_b, nm_w, nm_b,
                                     act_w, act_b, dec_w, dec_b,
                                     feats_h, finalv, nmbuf_h, qpack, out);
}

// Round 16
// 676.279 us; speedup vs baseline: 1.6448x; 1.1136x over previous
//
#include <hip/hip_runtime.h>
#include <math.h>

#define NN 1000
#define INF_ 32
#define H 128
#define M 128
#define DEG 16
#define PP 2
#define OUTF 10
#define MAXM (10 * NN)        // scan length; head <= MAXM
#define QCAP (MAXM + DEG)     // only entries < MAXM are ever read
#define NSLOT (MAXM + 128)    // nmbuf rows: nstart + total procs
#define NT 512                // 8 waves; steady-state VGPR < 128 (R12/R13 lesson)
#define WROW 264              // padded halves per X/weight row (256+8)
#define NROW 136              // padded halves per NSh row (128+8)

typedef _Float16 half8 __attribute__((ext_vector_type(8)));
typedef float floatx4 __attribute__((ext_vector_type(4)));

// LDS-only barrier: publishes LDS writes without draining global (vmcnt) queue.
__device__ __forceinline__ void bar_lds() {
    asm volatile("s_waitcnt lgkmcnt(0)\n\ts_barrier" ::: "memory");
}

// Parallel init (R14 lesson: never serialize this into seq_kernel).
// Blocks 0..NN-1: encoder + finalv zero + first messages.
// Blocks 0..263 additionally pack weights fp16 transposed [n][k] (+8 pad).
__global__ __launch_bounds__(128)
void init_kernel(const float* __restrict__ xa, const float* __restrict__ fm,
                 const float* __restrict__ enc_w, const float* __restrict__ enc_b,
                 const float* __restrict__ ns_w, const float* __restrict__ nm_w,
                 const int* __restrict__ nstart_p,
                 _Float16* __restrict__ feats_h, float* __restrict__ finalv,
                 _Float16* __restrict__ nmbuf_h,
                 _Float16* __restrict__ wnsB, _Float16* __restrict__ wnmB) {
    const int b = blockIdx.x, t = threadIdx.x;
    float acc = enc_b[t];
    const float* xr = xa + b * INF_;
#pragma unroll
    for (int k = 0; k < INF_; ++k) acc += xr[k] * enc_w[k * H + t];
    feats_h[b * H + t] = (_Float16)acc;     // same rounding as R8..R15
    finalv[b * H + t] = 0.0f;
    if (b < nstart_p[0]) nmbuf_h[(size_t)b * M + t] = (_Float16)fm[b * M + t];
    const int idx = b * 128 + t;            // weight pack: 128*WROW = 33792 elems
    if (idx < 128 * WROW) {
        const int n = idx / WROW, k = idx % WROW;
        wnsB[idx] = (k < 256) ? (_Float16)ns_w[k * H + n] : (_Float16)0.0f;
        wnmB[idx] = (k < 256) ? (_Float16)nm_w[k * M + n] : (_Float16)0.0f;
    }
}

// Rank-decomposed sequential ACT loop; MFMA matvecs, register-resident weight
// B-fragments (b128 loads from packed array); epoch-tagged node marks (no
// resets); per-wave atomicAdd rank (no R2 barrier); 3 LDS barriers per chunk
// with single-sigmoid s_rna (R11 form — R15's per-lane recompute regressed).
__global__ __launch_bounds__(NT, 1)
void seq_kernel(const int* __restrict__ neighbors, const int* __restrict__ nstart_p,
                const _Float16* __restrict__ wnsB, const _Float16* __restrict__ wnmB,
                const float* __restrict__ ns_b, const float* __restrict__ nm_b,
                const float* __restrict__ act_w, const float* __restrict__ act_b,
                const float* __restrict__ dec_w, const float* __restrict__ dec_b,
                _Float16* __restrict__ feats_h, float* __restrict__ finalv,
                _Float16* __restrict__ nmbuf_h, unsigned int* __restrict__ qpack,
                float* __restrict__ out) {
    __shared__ __align__(16) _Float16 s_Xh[16 * WROW];   // 8448 B
    __shared__ __align__(16) _Float16 s_NSh[16 * NROW];  // 4352 B
    __shared__ float s_tact[NN];                         // 4000 B
    __shared__ int   s_mark[NN];                         // 4000 B (readout overlay)
    __shared__ float s_rz[16];
    __shared__ float s_rna[16];
    __shared__ float s_rta[NT];                          // round-start tact per row
    __shared__ unsigned short s_rnode[NT];
    __shared__ unsigned short s_rslot[NT];
    __shared__ unsigned int  s_enq[NT];                  // node|newslot<<16 per entry
    __shared__ unsigned char s_flag[NT];
    __shared__ int s_wc[8];
    __shared__ int s_cnt;

    short* s_order = (short*)s_rta;                      // overlay: dead between windows
    float* s_g  = (float*)(s_mark);                      // overlay: readout only
    float* s_lg = (float*)(s_mark + 128);

    const int t = threadIdx.x;
    const int lane = t & 63, wid = t >> 6;
    const int quad = lane >> 4, lm = lane & 15;
    const int colw = (wid << 4) + lm;                    // this thread's output col
    const int sg = t & 31;                               // gate sub-lane
    const int r16 = t >> 5, c8 = t & 31;                 // staging coords (16x32)
    const int nstart = nstart_p[0];

    // ---- prologue: weight B-fragments via coalesced b128 loads ----
    half8 wbn[8], wbm[8];
#pragma unroll
    for (int c = 0; c < 8; ++c) {
        wbn[c] = *(const half8*)(wnsB + (size_t)colw * WROW + (c << 5) + (quad << 3));
        wbm[c] = *(const half8*)(wnmB + (size_t)colw * WROW + (c << 5) + (quad << 3));
    }
    for (int i = t; i < NN; i += NT) { s_tact[i] = 0.0f; s_mark[i] = 0x7fffffff; }
    for (int i = t; i < nstart; i += NT) qpack[i] = (unsigned)i | ((unsigned)i << 16);
    const float actb = act_b[0];
    const float nsb_c = ns_b[colw];
    const float nmb_c = nm_b[colw];
    float aw[8];
#pragma unroll
    for (int j = 0; j < 8; ++j) aw[j] = act_w[sg * 8 + j];
    __syncthreads();

    int head = 0, tail = nstart, gbase = nstart;
    int epoch = 0;                                       // global round counter
    for (;;) {
        const int lim = min(tail, MAXM);
        if (head >= lim) break;
        const int W = min(NT, lim - head);

        // ---- classify; clear flags ----
        int node = 0, slotv = 0; bool cand0 = false;
        if (t < W) {
            const unsigned v = qpack[head + t];
            node = (int)(v & 0xffffu);
            slotv = (int)(v >> 16);
            cand0 = (s_tact[node] <= 1.0f - 1e-7f);
        }
        s_flag[t] = 0;
        bar_lds();                                       // B1
        bool remaining = cand0;

        // ---------------- rank rounds ----------------
        int base = 0;
        for (;;) {
            ++epoch;                                     // < 32768 total rounds
            const int ec = ((0x7fff - epoch) << 16) | t; // smaller = newer epoch
            float tav = 0.0f;
            bool rem2 = false;
            if (remaining) { tav = s_tact[node]; rem2 = (tav <= 1.0f - 1e-7f); }
            if (t == 0) s_cnt = 0;
            if (rem2) atomicMin(&s_mark[node], ec);
            bar_lds();                                   // R1
            const bool win = rem2 && (s_mark[node] == ec);  // stale epochs never match
            // per-wave rank: one LDS atomic per wave (lane0), in-wave offset by mask
            const unsigned long long mw = __ballot(win);
            int wbase = 0;
            if (lane == 0 && mw) wbase = atomicAdd(&s_cnt, __popcll(mw));
            wbase = __builtin_amdgcn_readfirstlane(wbase);
            if (win) {
                const int wrank = wbase + __popcll(mw & ((1ull << lane) - 1ull));
                s_rnode[wrank] = (unsigned short)node;
                s_rslot[wrank] = (unsigned short)slotv;
                s_rta[wrank] = tav;
                s_enq[t] = (unsigned)node | ((unsigned)(gbase + base + wrank) << 16);
                s_flag[t] = 1;
            }
            remaining = rem2 && !win;
            bar_lds();                                   // R3: cnt/rnode/rslot/rta ready
            const int Pr = s_cnt;
            if (Pr == 0) break;

            // ---- prefetch chunk 0 (X row uint4 + finalv vals) ----
            uint4 px; float fv[4];
            {
                const int rr = min(r16, Pr - 1);
                const int nr = (int)s_rnode[rr];
                const int sl = (int)s_rslot[rr];
                px = (c8 < 16)
                    ? ((const uint4*)(feats_h + (size_t)nr * H))[c8]
                    : ((const uint4*)(nmbuf_h + (size_t)sl * M))[c8 - 16];
#pragma unroll
                for (int i = 0; i < 4; ++i) {
                    const int rr2 = min((quad << 2) + i, Pr - 1);
                    fv[i] = finalv[(size_t)s_rnode[rr2] * H + colw];
                }
            }
            // ---- chunks of 16 rows, software-pipelined staging ----
            for (int c0 = 0; c0 < Pr; c0 += 16) {
                const int Pc = min(16, Pr - c0);
                *(uint4*)(s_Xh + r16 * WROW + (c8 << 3)) = px;
                bar_lds();                               // A: Xh(c) ready
                const bool hasnext = (c0 + 16) < Pr;
                uint4 pxn; float fvn[4];
                if (hasnext) {                           // issue next-chunk loads
                    const int rr = min(c0 + 16 + r16, Pr - 1);
                    const int nr = (int)s_rnode[rr];
                    const int sl = (int)s_rslot[rr];
                    pxn = (c8 < 16)
                        ? ((const uint4*)(feats_h + (size_t)nr * H))[c8]
                        : ((const uint4*)(nmbuf_h + (size_t)sl * M))[c8 - 16];
#pragma unroll
                    for (int i = 0; i < 4; ++i) {
                        const int rr2 = min(c0 + 16 + (quad << 2) + i, Pr - 1);
                        fvn[i] = finalv[(size_t)s_rnode[rr2] * H + colw];
                    }
                }
                // gate partials (f32 math on fp16 x; coeffs in regs)
                {
                    const int r = t >> 5;
                    if (r < Pc) {
                        const half8 hv = *(const half8*)(s_Xh + r * WROW + (sg << 3));
                        float p = 0.0f;
#pragma unroll
                        for (int j = 0; j < 8; ++j) p += (float)hv[j] * aw[j];
#pragma unroll
                        for (int off = 16; off > 0; off >>= 1) p += __shfl_down(p, off, 32);
                        if (sg == 0) s_rz[r] = p;
                    }
                }
                // phase 1 MFMA: ns (K=256) + nm msg-half (K=128..256); B from regs
                floatx4 accn = {0.0f, 0.0f, 0.0f, 0.0f};
                floatx4 accm = {0.0f, 0.0f, 0.0f, 0.0f};
                {
                    const _Float16* xrow = s_Xh + lm * WROW + (quad << 3);
                    half8 a[8];
#pragma unroll
                    for (int c = 0; c < 8; ++c) a[c] = *(const half8*)(xrow + (c << 5));
#pragma unroll
                    for (int c = 0; c < 8; ++c)
                        accn = __builtin_amdgcn_mfma_f32_16x16x32_f16(
                            a[c], wbn[c], accn, 0, 0, 0);
#pragma unroll
                    for (int c = 4; c < 8; ++c)
                        accm = __builtin_amdgcn_mfma_f32_16x16x32_f16(
                            a[c], wbm[c], accm, 0, 0, 0);
                }
                float nsv[4];
#pragma unroll
                for (int i = 0; i < 4; ++i) {
                    const int r = (quad << 2) + i;
                    nsv[i] = fmaxf(accn[i] + nsb_c, 0.0f);
                    if (r < Pc) {
                        s_NSh[r * NROW + colw] = (_Float16)nsv[i];
                        feats_h[(size_t)s_rnode[c0 + r] * H + colw] = (_Float16)nsv[i];
                    }
                }
                bar_lds();                               // B: Xh reads done; NSh+rz ready

                // gate finalize + tact: ONE sigmoid per row (R11 form)
                if (t < Pc) {
                    const float z = s_rz[t] + actb;
                    const float cnd = 1.0f / (1.0f + expf(-z));
                    const float ta = s_rta[c0 + t];
                    const float na = (ta + cnd > 1.0f) ? (1.0f - ta) : cnd;
                    s_rna[t] = na;
                    s_tact[(int)s_rnode[c0 + t]] = ta + na;
                }
                // phase 2 MFMA: nm ns-half (K=0..128); B from regs; nmbuf store
                {
                    const _Float16* nrow = s_NSh + lm * NROW + (quad << 3);
#pragma unroll
                    for (int c = 0; c < 4; ++c)
                        accm = __builtin_amdgcn_mfma_f32_16x16x32_f16(
                            *(const half8*)(nrow + (c << 5)), wbm[c], accm, 0, 0, 0);
                }
#pragma unroll
                for (int i = 0; i < 4; ++i) {
                    const int r = (quad << 2) + i;
                    if (r < Pc)
                        nmbuf_h[(size_t)(gbase + base + c0 + r) * M + colw] =
                            (_Float16)(accm[i] + nmb_c);
                }
                bar_lds();                               // C: rna ready
                // epilogue: finalv with published rna (prefetched old value)
#pragma unroll
                for (int i = 0; i < 4; ++i) {
                    const int r = (quad << 2) + i;
                    if (r < Pc)
                        finalv[(size_t)s_rnode[c0 + r] * H + colw] =
                            fv[i] + nsv[i] * s_rna[r];
                }
                if (hasnext) {
                    px = pxn;
#pragma unroll
                    for (int i = 0; i < 4; ++i) fv[i] = fvn[i];
                }
            }
            base += Pr;
            __syncthreads();       // R7 (full): drain feats/nmbuf/finalv stores
        }

        // ---------------- enqueue (queue order via prefix over flags) ----------------
        const bool pf = (s_flag[t] != 0);
        const unsigned long long mf = __ballot(pf);
        if (lane == 0) s_wc[wid] = __popcll(mf);
        bar_lds();                                       // B3
        int T = 0, prec = 0;
#pragma unroll
        for (int w = 0; w < 8; ++w) { T += s_wc[w]; prec += (w < wid) ? s_wc[w] : 0; }
        if (pf) s_order[prec + __popcll(mf & ((1ull << lane) - 1ull))] = (short)t;
        bar_lds();                                       // B4
        for (int idx = t; idx < T * DEG; idx += NT) {
            const int e = (int)s_order[idx >> 4];
            const unsigned v = s_enq[e];
            const int nd = (int)(v & 0xffffu);
            const unsigned slot = v >> 16;
            const int q = tail + idx;
            if (q < QCAP)
                qpack[q] = (unsigned)neighbors[nd * DEG + (idx & 15)] | (slot << 16);
        }
        tail += DEG * T;
        gbase += T;
        head += W;
        __syncthreads();                                 // B5 (full): qpack visible
    }

    // ---- readout (g/lg overlaid on dead mark region) ----
    if (t < H) {
        float g0 = 0, g1 = 0, g2 = 0, g3 = 0;
        for (int n = 0; n < NN; n += 4) {
            g0 += finalv[(n + 0) * H + t];
            g1 += finalv[(n + 1) * H + t];
            g2 += finalv[(n + 2) * H + t];
            g3 += finalv[(n + 3) * H + t];
        }
        s_g[t] = (g0 + g1) + (g2 + g3);
    }
    __syncthreads();
    if (t < PP * OUTF) {
        const int pp = t / OUTF, o = t % OUTF;
        float acc = dec_b[pp * OUTF + o];
        for (int h = 0; h < H; ++h) acc += s_g[h] * dec_w[(pp * H + h) * OUTF + o];
        s_lg[t] = acc;
    }
    __syncthreads();
    if (t < PP * OUTF) {
        const int pp = t / OUTF;
        float mx = -INFINITY;
        for (int o = 0; o < OUTF; ++o) mx = fmaxf(mx, s_lg[pp * OUTF + o]);
        float s = 0.0f;
        for (int o = 0; o < OUTF; ++o) s += expf(s_lg[pp * OUTF + o] - mx);
        out[t] = s_lg[t] - (mx + logf(s));
    }
}

extern "C" void kernel_launch(void* const* d_in, const int* in_sizes, int n_in,
                              void* d_out, int out_size, void* d_ws, size_t ws_size,
                              hipStream_t stream) {
    const float* xa        = (const float*)d_in[0];
    const float* fm        = (const float*)d_in[1];
    const int*   neighbors = (const int*)  d_in[2];
    const int*   nstart_p  = (const int*)  d_in[3];
    const float* enc_w     = (const float*)d_in[4];
    const float* enc_b     = (const float*)d_in[5];
    const float* ns_w      = (const float*)d_in[6];
    const float* ns_b      = (const float*)d_in[7];
    const float* nm_w      = (const float*)d_in[8];
    const float* nm_b      = (const float*)d_in[9];
    const float* act_w     = (const float*)d_in[10];
    const float* act_b     = (const float*)d_in[11];
    const float* dec_w     = (const float*)d_in[12];
    const float* dec_b     = (const float*)d_in[13];
    float* out = (float*)d_out;

    char* w = (char*)d_ws;
    _Float16* feats_h = (_Float16*)w;                 w += (size_t)NN * H * 2;
    float*    finalv  = (float*)w;                    w += (size_t)NN * H * 4;
    _Float16* nmbuf_h = (_Float16*)w;                 w += (size_t)NSLOT * M * 2;
    _Float16* wnsB    = (_Float16*)w;                 w += (size_t)128 * WROW * 2;
    _Float16* wnmB    = (_Float16*)w;                 w += (size_t)128 * WROW * 2;
    unsigned int* qpack = (unsigned int*)w;

    init_kernel<<<NN, 128, 0, stream>>>(xa, fm, enc_w, enc_b, ns_w, nm_w,
                                        nstart_p, feats_h, finalv, nmbuf_h,
                                        wnsB, wnmB);
    seq_kernel<<<1, NT, 0, stream>>>(neighbors, nstart_p, wnsB, wnmB,
                                     ns_b, nm_b, act_w, act_b, dec_w, dec_b,
                                     feats_h, finalv, nmbuf_h, qpack, out);
}